// Round 1
// baseline (440.732 us; speedup 1.0000x reference)
//
#include <hip/hip_runtime.h>
#include <hip/hip_bf16.h>
#include <math.h>

#define B_   2
#define S_   2048
#define HID_ 2048
#define NH_  16
#define HD_  128
#define QKV_ (3 * NH_ * HD_)   // 6144
#define EPS_ 1e-5f

typedef __bf16 bf16x8 __attribute__((ext_vector_type(8)));
typedef __bf16 bf16x4 __attribute__((ext_vector_type(4)));
typedef __bf16 bf16x2 __attribute__((ext_vector_type(2)));
typedef float  f32x4  __attribute__((ext_vector_type(4)));

// ---------------------------------------------------------------------------
// fp32 -> bf16 cast for all three inputs in ONE launch.
// ---------------------------------------------------------------------------
__global__ __launch_bounds__(256) void cast3_f32_bf16(
    const float* __restrict__ a, __bf16* __restrict__ ao, int na4,
    const float* __restrict__ b, __bf16* __restrict__ bo, int nb4,
    const float* __restrict__ c, __bf16* __restrict__ co, int nc4) {
    int j = blockIdx.x * 256 + threadIdx.x;
    const float* src;
    __bf16* dst;
    if (j < na4) {
        src = a; dst = ao;
    } else {
        j -= na4;
        if (j < nb4) {
            src = b; dst = bo;
        } else {
            j -= nb4;
            if (j >= nc4) return;
            src = c; dst = co;
        }
    }
    float4 v = reinterpret_cast<const float4*>(src)[j];
    bf16x4 o = {(__bf16)v.x, (__bf16)v.y, (__bf16)v.z, (__bf16)v.w};
    reinterpret_cast<bf16x4*>(dst)[j] = o;
}

// ---------------------------------------------------------------------------
// bf16 MFMA GEMM (NT): C[M,N] = A[M,K] * B[N,K]^T  (unchanged, round-2 proven)
// ---------------------------------------------------------------------------
__device__ __forceinline__ void gload_lds16(const __bf16* g, __bf16* l) {
    __builtin_amdgcn_global_load_lds(
        (const __attribute__((address_space(1))) void*)g,
        (__attribute__((address_space(3))) void*)l, 16, 0, 0);
}

template <typename OutT>
__global__ __launch_bounds__(256) void gemm_bt_mfma(
    const __bf16* __restrict__ A, const __bf16* __restrict__ Bm,
    OutT* __restrict__ C, int M, int N, int K) {
    __shared__ __bf16 As[128 * 32];
    __shared__ __bf16 Bs[128 * 32];

    const int tid  = threadIdx.x;
    const int w    = tid >> 6;
    const int lane = tid & 63;
    const int wh   = w >> 1;
    const int ww   = w & 1;
    const int lrow = lane & 15;
    const int quad = lane >> 4;
    const int m0 = blockIdx.y * 128;
    const int n0 = blockIdx.x * 128;

    f32x4 acc[4][4] = {};

    for (int k0 = 0; k0 < K; k0 += 32) {
        __syncthreads();
#pragma unroll
        for (int t = 0; t < 2; ++t) {
            int c   = (w * 2 + t) * 64 + lane;
            int row = c >> 2;
            int kc  = (c & 3) * 8;
            gload_lds16(&A[(size_t)(m0 + row) * K + k0 + kc],
                        &As[(w * 2 + t) * 512]);
            gload_lds16(&Bm[(size_t)(n0 + row) * K + k0 + kc],
                        &Bs[(w * 2 + t) * 512]);
        }
        __syncthreads();

        bf16x8 af[4], bf[4];
#pragma unroll
        for (int i = 0; i < 4; ++i)
            af[i] = *reinterpret_cast<const bf16x8*>(
                &As[(wh * 64 + i * 16 + lrow) * 32 + quad * 8]);
#pragma unroll
        for (int j = 0; j < 4; ++j)
            bf[j] = *reinterpret_cast<const bf16x8*>(
                &Bs[(ww * 64 + j * 16 + lrow) * 32 + quad * 8]);
#pragma unroll
        for (int i = 0; i < 4; ++i)
#pragma unroll
            for (int j = 0; j < 4; ++j)
                acc[i][j] = __builtin_amdgcn_mfma_f32_16x16x32_bf16(
                    af[i], bf[j], acc[i][j], 0, 0, 0);
    }

#pragma unroll
    for (int i = 0; i < 4; ++i) {
#pragma unroll
        for (int r = 0; r < 4; ++r) {
            int row = m0 + wh * 64 + i * 16 + quad * 4 + r;
            size_t base = (size_t)row * N + n0 + ww * 64 + lrow;
#pragma unroll
            for (int j = 0; j < 4; ++j) {
                float v = acc[i][j][r];
                C[base + j * 16] = (OutT)v;
            }
        }
    }
}

// ---------------------------------------------------------------------------
// RMSNorm (flat 2048) + RoPE in place on bf16 q or k.  (unchanged)
// ---------------------------------------------------------------------------
__global__ __launch_bounds__(256) void normrope_kernel(
    __bf16* __restrict__ qkv, const float* __restrict__ qw,
    const float* __restrict__ kw) {
    const int row = blockIdx.x;
    const int sel = blockIdx.y;
    const int pos = row & (S_ - 1);
    __bf16* p = qkv + (size_t)row * QKV_ + sel * 2048;
    const float* w = sel ? kw : qw;

    __shared__ float buf[2048];
    __shared__ float red[4];
    const int tid = threadIdx.x;
    const int e   = tid * 8;

    bf16x8 t = *reinterpret_cast<const bf16x8*>(&p[e]);
    float xs[8];
    float ss = 0.f;
#pragma unroll
    for (int u = 0; u < 8; ++u) {
        xs[u] = (float)t[u];
        buf[e + u] = xs[u];
        ss += xs[u] * xs[u];
    }
#pragma unroll
    for (int off = 32; off > 0; off >>= 1) ss += __shfl_xor(ss, off, 64);
    if ((tid & 63) == 0) red[tid >> 6] = ss;
    __syncthreads();
    float total = red[0] + red[1] + red[2] + red[3];
    float scale = rsqrtf(total * (1.f / 2048.f) + EPS_);

    const float kfreq2 = -0.20762050593046f;  // -log2(10000)/64
    const int jbase = e & 63;
    const bool first = (e & 127) < 64;
    const int ep = e ^ 64;

    float ps[8], ws[8], pw[8];
#pragma unroll
    for (int u = 0; u < 8; ++u) ps[u] = buf[ep + u];
    float4 w0 = *reinterpret_cast<const float4*>(&w[e]);
    float4 w1 = *reinterpret_cast<const float4*>(&w[e + 4]);
    float4 p0 = *reinterpret_cast<const float4*>(&w[ep]);
    float4 p1 = *reinterpret_cast<const float4*>(&w[ep + 4]);
    ws[0]=w0.x; ws[1]=w0.y; ws[2]=w0.z; ws[3]=w0.w;
    ws[4]=w1.x; ws[5]=w1.y; ws[6]=w1.z; ws[7]=w1.w;
    pw[0]=p0.x; pw[1]=p0.y; pw[2]=p0.z; pw[3]=p0.w;
    pw[4]=p1.x; pw[5]=p1.y; pw[6]=p1.z; pw[7]=p1.w;

    bf16x8 o8;
#pragma unroll
    for (int u = 0; u < 8; ++u) {
        float inv_freq = exp2f((float)(jbase + u) * kfreq2);
        float ang = (float)pos * inv_freq;
        float sn = __sinf(ang);
        float cs = __cosf(ang);
        float a  = xs[u] * scale * ws[u];
        float bb = ps[u] * scale * pw[u];
        float o  = first ? (a * cs - bb * sn) : (a * cs + bb * sn);
        o8[u] = (__bf16)o;
    }
    *reinterpret_cast<bf16x8*>(&p[e]) = o8;
}

// ---------------------------------------------------------------------------
// MFMA flash attention, S^T + static-max softmax + PREFETCH-1 pipeline.
//
// R(this): 128-row Q-tile via 512-thread/8-wave blocks (per-wave code is the
// proven 16-row strip, unchanged). Halves block count -> halves K/V staging
// traffic, barriers, and Vt writes per q-row. Grid flattened to 512 blocks
// with a bijective XCD swizzle: each XCD owns 4 contiguous bh's = 4 MB of
// K/V = its whole L2, so the 16 q-tiles of a head re-read K/V from L2, not
// HBM. s_setprio(1) wrapped around both MFMA clusters (+4-7% measured on
// attn-shaped kernels, m191).
//
// Pipeline per iteration kt (ping-pong buffers), same proven structure:
//   1. write V-regs(kt) -> Vt[buf]        (regs loaded during iter kt-1)
//   2. __syncthreads()                    (K(kt) gload_lds drained here —
//                                          issued last iter, drain prepaid)
//   3. issue prefetch kt+1: gload_lds K -> Ks[buf^1]; global V -> regs
//   4. compute on buf
// Safety: writes to a buffer only occur after the barrier fencing all waves'
// reads of that buffer (reads in iter kt-2's compute, fenced at iter kt-1).
// ---------------------------------------------------------------------------
#define VTP 36   // Vt/Pb row stride in bf16: 72B rows, 2-way-max aliasing

__global__ __launch_bounds__(512, 4) void attn_mfma(
    const __bf16* __restrict__ qkv, __bf16* __restrict__ aout) {
    // 512 blocks; bijective XCD swizzle (512 % 8 == 0): XCD c gets
    // vid in [c*64, c*64+64) = bh in [c*4, c*4+4), 16 q-tiles each.
    const int flat = (int)blockIdx.x;
    const int vid  = (flat & 7) * 64 + (flat >> 3);
    const int bh   = vid >> 4;
    const int qt   = 15 - (vid & 15);     // heavy diagonal tiles first
    const int b    = bh >> 4;
    const int h    = bh & (NH_ - 1);
    const int q0   = qt * 128;
    const int tid  = threadIdx.x;
    const int w    = tid >> 6;            // 0..7
    const int lane = tid & 63;
    const int lrow = lane & 15;
    const int quad = lane >> 4;

    __shared__ __bf16 Ks[2][4][32 * 32];   // [buf][kc][key*32+c]  16 KB
    __shared__ __bf16 Vt[2][128 * VTP];    // [buf][d*VTP+key]     18 KB
    __shared__ __bf16 Pb[8][16 * VTP];     // [wave][q*VTP+key]     9 KB

    const size_t base = (size_t)(b * S_) * QKV_ + (size_t)h * HD_;
    const int qrow = q0 + w * 16 + lrow;   // this lane's q-row (B-frag n)

    // resident Q B-frags: [n=qrow][k = kc*32 + quad*8 + j]
    bf16x8 qf[4];
#pragma unroll
    for (int kc = 0; kc < 4; ++kc)
        qf[kc] = *reinterpret_cast<const bf16x8*>(
            &qkv[base + (size_t)qrow * QKV_ + kc * 32 + quad * 8]);

    f32x4 o[8] = {};          // O^T: d = dt*16+quad*4+r, q = lrow
    float lpart = 0.f;        // per-lane partial sum of p

    const int ktmax_w   = 4 * qt + (w >> 1);  // wave's diagonal tile
    const int ktmax_blk = 4 * qt + 3;
    const float sl2 = 0.12751743671f;   // (1/sqrt(128))*log2(e)

    // K staging: wave w stages chunk (w>>1), key-half (w&1): one gload each.
    const __bf16* kg0 = qkv + base + 2048 +
                        (size_t)((w & 1) * 16 + (lane >> 2)) * QKV_ +
                        (w >> 1) * 32 + (lane & 3) * 8;
    // V staging: waves 0-3 only (256 threads), g = tid>>4 (d-group),
    // kp = tid&15 (key pair) — identical to the proven layout.
    const int g  = tid >> 4;
    const int kp = tid & 15;
    const __bf16* vg0 = qkv + base + 4096 + (size_t)(kp * 2) * QKV_ + g * 8;

    // ---- preload tile 0: K direct-to-LDS buf0, V into regs ----
    gload_lds16(kg0, &Ks[0][w >> 1][(w & 1) * 512]);
    bf16x8 v0 = {}, v1 = {};
    if (tid < 256) {
        v0 = *reinterpret_cast<const bf16x8*>(vg0);
        v1 = *reinterpret_cast<const bf16x8*>(vg0 + QKV_);
    }

    for (int kt = 0; kt <= ktmax_blk; ++kt) {
        const int buf = kt & 1;
        // 1. V regs (tile kt) -> Vt[buf] (prior reads fenced at iter kt-1)
        if (tid < 256) {
#pragma unroll
            for (int u = 0; u < 8; ++u) {
                bf16x2 pr = {v0[u], v1[u]};
                *reinterpret_cast<bf16x2*>(
                    &Vt[buf][(g * 8 + u) * VTP + kp * 2]) = pr;
            }
        }
        // 2. barrier: Ks[buf]/Vt[buf] ready for all waves
        __syncthreads();
        // 3. prefetch tile kt+1 into the other buffer / regs
        if (kt < ktmax_blk) {
            const __bf16* kg = kg0 + (size_t)(kt + 1) * 32 * QKV_;
            gload_lds16(kg, &Ks[buf ^ 1][w >> 1][(w & 1) * 512]);
            if (tid < 256) {
                const __bf16* vg = vg0 + (size_t)(kt + 1) * 32 * QKV_;
                v0 = *reinterpret_cast<const bf16x8*>(vg);
                v1 = *reinterpret_cast<const bf16x8*>(vg + QKV_);
            }
        }
        // 4. compute on buf
        if (kt <= ktmax_w) {   // wave-uniform causal skip
            // ---- S^T = K Q^T : 8 MFMAs ----
            f32x4 sc[2] = {};
            __builtin_amdgcn_s_setprio(1);
#pragma unroll
            for (int kc = 0; kc < 4; ++kc) {
                bf16x8 kf0 = *reinterpret_cast<const bf16x8*>(
                    &Ks[buf][kc][lrow * 32 + quad * 8]);
                bf16x8 kf1 = *reinterpret_cast<const bf16x8*>(
                    &Ks[buf][kc][(16 + lrow) * 32 + quad * 8]);
                sc[0] = __builtin_amdgcn_mfma_f32_16x16x32_bf16(
                    kf0, qf[kc], sc[0], 0, 0, 0);
                sc[1] = __builtin_amdgcn_mfma_f32_16x16x32_bf16(
                    kf1, qf[kc], sc[1], 0, 0, 0);
            }
            __builtin_amdgcn_s_setprio(0);
            // ---- static-max softmax: p = exp2(s*sl2 - 32) ----
            const bool diag = (kt == ktmax_w);
            float p[2][4];
#pragma unroll
            for (int m2 = 0; m2 < 2; ++m2)
#pragma unroll
                for (int r = 0; r < 4; ++r) {
                    float s = sc[m2][r] * sl2 - 32.f;
                    if (diag && kt * 32 + m2 * 16 + quad * 4 + r > qrow)
                        s = -1e30f;
                    p[m2][r] = exp2f(s);
                    lpart += p[m2][r];
                }
            // ---- P -> Pb[q][key] (B-frag layout), two b64 stores ----
#pragma unroll
            for (int m2 = 0; m2 < 2; ++m2) {
                bf16x4 pb = {(__bf16)p[m2][0], (__bf16)p[m2][1],
                             (__bf16)p[m2][2], (__bf16)p[m2][3]};
                *reinterpret_cast<bf16x4*>(
                    &Pb[w][lrow * VTP + m2 * 16 + quad * 4]) = pb;
            }
            bf16x8 pf = *reinterpret_cast<const bf16x8*>(
                &Pb[w][lrow * VTP + quad * 8]);
            // ---- O^T += V^T P^T : 8 MFMAs ----
            __builtin_amdgcn_s_setprio(1);
#pragma unroll
            for (int dt = 0; dt < 8; ++dt) {
                bf16x8 vf = *reinterpret_cast<const bf16x8*>(
                    &Vt[buf][(dt * 16 + lrow) * VTP + quad * 8]);
                o[dt] = __builtin_amdgcn_mfma_f32_16x16x32_bf16(
                    vf, pf, o[dt], 0, 0, 0);
            }
            __builtin_amdgcn_s_setprio(0);
        }
    }

    // epilogue: reduce l across the 4 quad-groups (same q-row), then scale
    lpart += __shfl_xor(lpart, 16, 64);
    lpart += __shfl_xor(lpart, 32, 64);
    const float invl = 1.f / lpart;
    const size_t orow = (size_t)(b * S_ + qrow) * (NH_ * HD_) + (size_t)h * HD_;
#pragma unroll
    for (int dt = 0; dt < 8; ++dt) {
        bf16x4 ov = {(__bf16)(o[dt][0] * invl), (__bf16)(o[dt][1] * invl),
                     (__bf16)(o[dt][2] * invl), (__bf16)(o[dt][3] * invl)};
        *reinterpret_cast<bf16x4*>(&aout[orow + dt * 16 + quad * 4]) = ov;
    }
}

// ---------------------------------------------------------------------------
extern "C" void kernel_launch(void* const* d_in, const int* in_sizes, int n_in,
                              void* d_out, int out_size, void* d_ws,
                              size_t ws_size, hipStream_t stream) {
    const float* x     = (const float*)d_in[0];
    const float* w_in  = (const float*)d_in[1];
    const float* w_out = (const float*)d_in[2];
    const float* qw    = (const float*)d_in[3];
    const float* kw    = (const float*)d_in[4];
    float* out = (float*)d_out;

    const int M = B_ * S_;  // 4096
    // workspace (bytes), peak 96 MiB:
    //   [0,48M) qkv_bf16 | [48M,56M) w_out_bf16 | [56M,72M) x_bf16/attn_bf16
    //   [72M,96M) w_in_bf16
    char* ws = (char*)d_ws;
    __bf16* qkv_b   = (__bf16*)(ws);
    __bf16* w_out_b = (__bf16*)(ws + (size_t)50331648);
    __bf16* x_b     = (__bf16*)(ws + (size_t)58720256);
    __bf16* attn_b  = x_b;  // x_bf16 dead after GEMM1
    __bf16* w_in_b  = (__bf16*)(ws + (size_t)75497472);

    dim3 blk(256);

    // single fused cast launch: x, w_in, w_out
    {
        const int na4 = (M * HID_) / 4;          // 2,097,152
        const int nb4 = (QKV_ * HID_) / 4;       // 3,145,728
        const int nc4 = (HID_ * NH_ * HD_) / 4;  // 1,048,576
        const int tot = na4 + nb4 + nc4;
        cast3_f32_bf16<<<dim3((tot + 255) / 256), blk, 0, stream>>>(
            x, x_b, na4, w_in, w_in_b, nb4, w_out, w_out_b, nc4);
    }

    // qkv = x @ w_in^T   (4096 x 6144 x 2048)
    gemm_bt_mfma<__bf16><<<dim3(QKV_ / 128, M / 128), blk, 0, stream>>>(
        x_b, w_in_b, qkv_b, M, QKV_, HID_);
    // rmsnorm + rope on q and k, in place
    normrope_kernel<<<dim3(M, 2), blk, 0, stream>>>(qkv_b, qw, kw);
    // causal MFMA flash attention: 128-row Q-tiles, 8 waves, XCD-swizzled
    attn_mfma<<<dim3((S_ / 128) * B_ * NH_), dim3(512), 0, stream>>>(
        qkv_b, attn_b);
    // out = attn @ w_out^T  (4096 x 2048 x 2048), fp32 out
    gemm_bt_mfma<float><<<dim3(HID_ / 128, M / 128), blk, 0, stream>>>(
        attn_b, w_out_b, out, M, HID_, NH_ * HD_);
}

// Round 2
// 416.952 us; speedup vs baseline: 1.0570x; 1.0570x over previous
//
#include <hip/hip_runtime.h>
#include <hip/hip_bf16.h>
#include <math.h>

#define B_   2
#define S_   2048
#define HID_ 2048
#define NH_  16
#define HD_  128
#define QKV_ (3 * NH_ * HD_)   // 6144
#define EPS_ 1e-5f

typedef __bf16 bf16x8 __attribute__((ext_vector_type(8)));
typedef __bf16 bf16x4 __attribute__((ext_vector_type(4)));
typedef __bf16 bf16x2 __attribute__((ext_vector_type(2)));
typedef float  f32x4  __attribute__((ext_vector_type(4)));

// ---------------------------------------------------------------------------
// fp32 -> bf16 cast for all three inputs in ONE launch.
// ---------------------------------------------------------------------------
__global__ __launch_bounds__(256) void cast3_f32_bf16(
    const float* __restrict__ a, __bf16* __restrict__ ao, int na4,
    const float* __restrict__ b, __bf16* __restrict__ bo, int nb4,
    const float* __restrict__ c, __bf16* __restrict__ co, int nc4) {
    int j = blockIdx.x * 256 + threadIdx.x;
    const float* src;
    __bf16* dst;
    if (j < na4) {
        src = a; dst = ao;
    } else {
        j -= na4;
        if (j < nb4) {
            src = b; dst = bo;
        } else {
            j -= nb4;
            if (j >= nc4) return;
            src = c; dst = co;
        }
    }
    float4 v = reinterpret_cast<const float4*>(src)[j];
    bf16x4 o = {(__bf16)v.x, (__bf16)v.y, (__bf16)v.z, (__bf16)v.w};
    reinterpret_cast<bf16x4*>(dst)[j] = o;
}

__device__ __forceinline__ void gload_lds16(const __bf16* g, __bf16* l) {
    __builtin_amdgcn_global_load_lds(
        (const __attribute__((address_space(1))) void*)g,
        (__attribute__((address_space(3))) void*)l, 16, 0, 0);
}

// ---------------------------------------------------------------------------
// 8-phase-style bf16 MFMA GEMM (NT): C[M,N] = A[M,K] * B[N,K]^T.
// Tile 128(M) x 256(N), BK=64, 512 thr = 8 waves (2Mx4N), wave tile 64x64.
// Ring of 3 LDS buffers (144 KB): iter t computes tile t from buf(t%3) and
// issues tile t+2 into buf((t+2)%3) -> steady-state s_waitcnt vmcnt(12)
// (counted, never 0 in loop; 12 = 6 loads/wave/tile x 2 tiles in flight).
// LDS XOR-swizzle (16B granule ^= row&7) applied via pre-swizzled GLOBAL
// source (gload_lds dest must stay linear) and the same XOR on ds_read.
// Raw s_barrier (no implicit vmcnt drain) + setprio(1) around MFMA clusters.
//
// Safety chain: per phase, ds_reads -> (register dep, compiler lgkmcnt) ->
// MFMAs -> trailing barrier; next iteration's stage-issue into a buffer only
// happens after the barrier that postdates all waves' MFMA consumption of it.
// vmcnt(N)+barrier before first ds_read of each tile guarantees all waves'
// DMA for that tile has landed.
// ---------------------------------------------------------------------------
__device__ __forceinline__ void stage_tile6(
    const __bf16* pA, const __bf16* pB, __bf16* buf, int w, int K) {
#pragma unroll
    for (int s = 0; s < 2; ++s)
        gload_lds16(pA + (size_t)s * 64 * K, buf + s * 4096 + w * 512);
#pragma unroll
    for (int s = 0; s < 4; ++s)
        gload_lds16(pB + (size_t)s * 64 * K, buf + 8192 + s * 4096 + w * 512);
}

template <typename OutT>
__global__ __launch_bounds__(512, 2) void gemm_bt_8ph(
    const __bf16* __restrict__ A, const __bf16* __restrict__ Bm,
    OutT* __restrict__ C, int M, int N, int K) {
    __shared__ __bf16 lds[3][24576];   // [buf][ A:128x64 | B:256x64 ] 144 KB

    const int tid  = threadIdx.x;
    const int w    = tid >> 6;         // 0..7
    const int lane = tid & 63;
    const int lrow = lane & 15;
    const int quad = lane >> 4;
    const int wm   = w >> 2;           // 0..1  (M half)
    const int wn   = w & 3;            // 0..3  (N quarter)

    // column-major block order + bijective XCD swizzle (gridDim.x % 8 == 0)
    const int chunk = (int)gridDim.x >> 3;
    const int flat  = (int)blockIdx.x;
    const int vid   = (flat & 7) * chunk + (flat >> 3);
    const int by    = vid & 31;        // M/128 = 32 for both GEMMs
    const int bx    = vid >> 5;
    const int m0 = by * 128;
    const int n0 = bx * 256;

    // staging source: thread covers LDS row (w*8+lr), 16B granule lg of each
    // 64-row call-chunk; global col granule pre-swizzled = lg ^ lr.
    const int lr = lane >> 3;
    const int lg = lane & 7;
    const __bf16* pA = A  + (size_t)(m0 + w * 8 + lr) * K + ((lg ^ lr) << 3);
    const __bf16* pB = Bm + (size_t)(n0 + w * 8 + lr) * K + ((lg ^ lr) << 3);

    const int nt = K >> 6;             // K-tiles of 64
    f32x4 acc[4][4] = {};

    // prologue: stage tiles 0,1 into bufs 0,1 (12 loads in flight)
    stage_tile6(pA, pB, &lds[0][0], w, K);
    stage_tile6(pA + 64, pB + 64, &lds[1][0], w, K);

    int cur = 0;
    for (int t = 0; t < nt; ++t) {
        __bf16* bufc = &lds[cur][0];
        int nxt = cur + 2; if (nxt >= 3) nxt -= 3;
        if (t + 2 < nt) {
            stage_tile6(pA + (size_t)(t + 2) * 64, pB + (size_t)(t + 2) * 64,
                        &lds[nxt][0], w, K);
            asm volatile("s_waitcnt vmcnt(12)" ::: "memory");
        } else if (t + 1 < nt) {
            asm volatile("s_waitcnt vmcnt(6)" ::: "memory");
        } else {
            asm volatile("s_waitcnt vmcnt(0)" ::: "memory");
        }
        __builtin_amdgcn_s_barrier();          // tile t fully in LDS, all waves
        asm volatile("" ::: "memory");

#pragma unroll
        for (int q = 0; q < 2; ++q) {          // 2 phases x 16 MFMA per K-tile
            bf16x8 af[2][2], bfv[4][2];
#pragma unroll
            for (int i = 0; i < 2; ++i)
#pragma unroll
                for (int kk = 0; kk < 2; ++kk)
                    af[i][kk] = *reinterpret_cast<const bf16x8*>(
                        &bufc[(wm * 64 + (q * 2 + i) * 16 + lrow) * 64 +
                              (((kk * 4 + quad) ^ (lrow & 7)) << 3)]);
#pragma unroll
            for (int j = 0; j < 4; ++j)
#pragma unroll
                for (int kk = 0; kk < 2; ++kk)
                    bfv[j][kk] = *reinterpret_cast<const bf16x8*>(
                        &bufc[8192 + (wn * 64 + j * 16 + lrow) * 64 +
                              (((kk * 4 + quad) ^ (lrow & 7)) << 3)]);
            __builtin_amdgcn_s_barrier();      // lockstep entry into MFMA
            asm volatile("" ::: "memory");
            __builtin_amdgcn_s_setprio(1);
#pragma unroll
            for (int i = 0; i < 2; ++i)
#pragma unroll
                for (int j = 0; j < 4; ++j)
#pragma unroll
                    for (int kk = 0; kk < 2; ++kk)
                        acc[q * 2 + i][j] =
                            __builtin_amdgcn_mfma_f32_16x16x32_bf16(
                                af[i][kk], bfv[j][kk], acc[q * 2 + i][j],
                                0, 0, 0);
            __builtin_amdgcn_s_setprio(0);
        }
        __builtin_amdgcn_s_barrier();          // fence reads before re-stage
        asm volatile("" ::: "memory");
        cur = (cur == 2) ? 0 : cur + 1;
    }

#pragma unroll
    for (int mi = 0; mi < 4; ++mi) {
#pragma unroll
        for (int r = 0; r < 4; ++r) {
            int row = m0 + wm * 64 + mi * 16 + quad * 4 + r;
            size_t basec = (size_t)row * N + n0 + wn * 64 + lrow;
#pragma unroll
            for (int nj = 0; nj < 4; ++nj)
                C[basec + nj * 16] = (OutT)acc[mi][nj][r];
        }
    }
}

// ---------------------------------------------------------------------------
// RMSNorm (flat 2048) + RoPE in place on bf16 q or k.  (unchanged)
// ---------------------------------------------------------------------------
__global__ __launch_bounds__(256) void normrope_kernel(
    __bf16* __restrict__ qkv, const float* __restrict__ qw,
    const float* __restrict__ kw) {
    const int row = blockIdx.x;
    const int sel = blockIdx.y;
    const int pos = row & (S_ - 1);
    __bf16* p = qkv + (size_t)row * QKV_ + sel * 2048;
    const float* w = sel ? kw : qw;

    __shared__ float buf[2048];
    __shared__ float red[4];
    const int tid = threadIdx.x;
    const int e   = tid * 8;

    bf16x8 t = *reinterpret_cast<const bf16x8*>(&p[e]);
    float xs[8];
    float ss = 0.f;
#pragma unroll
    for (int u = 0; u < 8; ++u) {
        xs[u] = (float)t[u];
        buf[e + u] = xs[u];
        ss += xs[u] * xs[u];
    }
#pragma unroll
    for (int off = 32; off > 0; off >>= 1) ss += __shfl_xor(ss, off, 64);
    if ((tid & 63) == 0) red[tid >> 6] = ss;
    __syncthreads();
    float total = red[0] + red[1] + red[2] + red[3];
    float scale = rsqrtf(total * (1.f / 2048.f) + EPS_);

    const float kfreq2 = -0.20762050593046f;  // -log2(10000)/64
    const int jbase = e & 63;
    const bool first = (e & 127) < 64;
    const int ep = e ^ 64;

    float ps[8], ws[8], pw[8];
#pragma unroll
    for (int u = 0; u < 8; ++u) ps[u] = buf[ep + u];
    float4 w0 = *reinterpret_cast<const float4*>(&w[e]);
    float4 w1 = *reinterpret_cast<const float4*>(&w[e + 4]);
    float4 p0 = *reinterpret_cast<const float4*>(&w[ep]);
    float4 p1 = *reinterpret_cast<const float4*>(&w[ep + 4]);
    ws[0]=w0.x; ws[1]=w0.y; ws[2]=w0.z; ws[3]=w0.w;
    ws[4]=w1.x; ws[5]=w1.y; ws[6]=w1.z; ws[7]=w1.w;
    pw[0]=p0.x; pw[1]=p0.y; pw[2]=p0.z; pw[3]=p0.w;
    pw[4]=p1.x; pw[5]=p1.y; pw[6]=p1.z; pw[7]=p1.w;

    bf16x8 o8;
#pragma unroll
    for (int u = 0; u < 8; ++u) {
        float inv_freq = exp2f((float)(jbase + u) * kfreq2);
        float ang = (float)pos * inv_freq;
        float sn = __sinf(ang);
        float cs = __cosf(ang);
        float a  = xs[u] * scale * ws[u];
        float bb = ps[u] * scale * pw[u];
        float o  = first ? (a * cs - bb * sn) : (a * cs + bb * sn);
        o8[u] = (__bf16)o;
    }
    *reinterpret_cast<bf16x8*>(&p[e]) = o8;
}

// ---------------------------------------------------------------------------
// MFMA flash attention (unchanged from R0: 128-row Q-tile, 8 waves,
// XCD-swizzled, setprio around MFMA clusters, prefetch-1 pipeline).
// ---------------------------------------------------------------------------
#define VTP 36   // Vt/Pb row stride in bf16: 72B rows, 2-way-max aliasing

__global__ __launch_bounds__(512, 4) void attn_mfma(
    const __bf16* __restrict__ qkv, __bf16* __restrict__ aout) {
    const int flat = (int)blockIdx.x;
    const int vid  = (flat & 7) * 64 + (flat >> 3);
    const int bh   = vid >> 4;
    const int qt   = 15 - (vid & 15);     // heavy diagonal tiles first
    const int b    = bh >> 4;
    const int h    = bh & (NH_ - 1);
    const int q0   = qt * 128;
    const int tid  = threadIdx.x;
    const int w    = tid >> 6;            // 0..7
    const int lane = tid & 63;
    const int lrow = lane & 15;
    const int quad = lane >> 4;

    __shared__ __bf16 Ks[2][4][32 * 32];   // [buf][kc][key*32+c]  16 KB
    __shared__ __bf16 Vt[2][128 * VTP];    // [buf][d*VTP+key]     18 KB
    __shared__ __bf16 Pb[8][16 * VTP];     // [wave][q*VTP+key]     9 KB

    const size_t base = (size_t)(b * S_) * QKV_ + (size_t)h * HD_;
    const int qrow = q0 + w * 16 + lrow;   // this lane's q-row (B-frag n)

    bf16x8 qf[4];
#pragma unroll
    for (int kc = 0; kc < 4; ++kc)
        qf[kc] = *reinterpret_cast<const bf16x8*>(
            &qkv[base + (size_t)qrow * QKV_ + kc * 32 + quad * 8]);

    f32x4 o[8] = {};          // O^T: d = dt*16+quad*4+r, q = lrow
    float lpart = 0.f;        // per-lane partial sum of p

    const int ktmax_w   = 4 * qt + (w >> 1);  // wave's diagonal tile
    const int ktmax_blk = 4 * qt + 3;
    const float sl2 = 0.12751743671f;   // (1/sqrt(128))*log2(e)

    const __bf16* kg0 = qkv + base + 2048 +
                        (size_t)((w & 1) * 16 + (lane >> 2)) * QKV_ +
                        (w >> 1) * 32 + (lane & 3) * 8;
    const int g  = tid >> 4;
    const int kp = tid & 15;
    const __bf16* vg0 = qkv + base + 4096 + (size_t)(kp * 2) * QKV_ + g * 8;

    gload_lds16(kg0, &Ks[0][w >> 1][(w & 1) * 512]);
    bf16x8 v0 = {}, v1 = {};
    if (tid < 256) {
        v0 = *reinterpret_cast<const bf16x8*>(vg0);
        v1 = *reinterpret_cast<const bf16x8*>(vg0 + QKV_);
    }

    for (int kt = 0; kt <= ktmax_blk; ++kt) {
        const int buf = kt & 1;
        if (tid < 256) {
#pragma unroll
            for (int u = 0; u < 8; ++u) {
                bf16x2 pr = {v0[u], v1[u]};
                *reinterpret_cast<bf16x2*>(
                    &Vt[buf][(g * 8 + u) * VTP + kp * 2]) = pr;
            }
        }
        __syncthreads();
        if (kt < ktmax_blk) {
            const __bf16* kg = kg0 + (size_t)(kt + 1) * 32 * QKV_;
            gload_lds16(kg, &Ks[buf ^ 1][w >> 1][(w & 1) * 512]);
            if (tid < 256) {
                const __bf16* vg = vg0 + (size_t)(kt + 1) * 32 * QKV_;
                v0 = *reinterpret_cast<const bf16x8*>(vg);
                v1 = *reinterpret_cast<const bf16x8*>(vg + QKV_);
            }
        }
        if (kt <= ktmax_w) {   // wave-uniform causal skip
            f32x4 sc[2] = {};
            __builtin_amdgcn_s_setprio(1);
#pragma unroll
            for (int kc = 0; kc < 4; ++kc) {
                bf16x8 kf0 = *reinterpret_cast<const bf16x8*>(
                    &Ks[buf][kc][lrow * 32 + quad * 8]);
                bf16x8 kf1 = *reinterpret_cast<const bf16x8*>(
                    &Ks[buf][kc][(16 + lrow) * 32 + quad * 8]);
                sc[0] = __builtin_amdgcn_mfma_f32_16x16x32_bf16(
                    kf0, qf[kc], sc[0], 0, 0, 0);
                sc[1] = __builtin_amdgcn_mfma_f32_16x16x32_bf16(
                    kf1, qf[kc], sc[1], 0, 0, 0);
            }
            __builtin_amdgcn_s_setprio(0);
            const bool diag = (kt == ktmax_w);
            float p[2][4];
#pragma unroll
            for (int m2 = 0; m2 < 2; ++m2)
#pragma unroll
                for (int r = 0; r < 4; ++r) {
                    float s = sc[m2][r] * sl2 - 32.f;
                    if (diag && kt * 32 + m2 * 16 + quad * 4 + r > qrow)
                        s = -1e30f;
                    p[m2][r] = exp2f(s);
                    lpart += p[m2][r];
                }
#pragma unroll
            for (int m2 = 0; m2 < 2; ++m2) {
                bf16x4 pb = {(__bf16)p[m2][0], (__bf16)p[m2][1],
                             (__bf16)p[m2][2], (__bf16)p[m2][3]};
                *reinterpret_cast<bf16x4*>(
                    &Pb[w][lrow * VTP + m2 * 16 + quad * 4]) = pb;
            }
            bf16x8 pf = *reinterpret_cast<const bf16x8*>(
                &Pb[w][lrow * VTP + quad * 8]);
            __builtin_amdgcn_s_setprio(1);
#pragma unroll
            for (int dt = 0; dt < 8; ++dt) {
                bf16x8 vf = *reinterpret_cast<const bf16x8*>(
                    &Vt[buf][(dt * 16 + lrow) * VTP + quad * 8]);
                o[dt] = __builtin_amdgcn_mfma_f32_16x16x32_bf16(
                    vf, pf, o[dt], 0, 0, 0);
            }
            __builtin_amdgcn_s_setprio(0);
        }
    }

    lpart += __shfl_xor(lpart, 16, 64);
    lpart += __shfl_xor(lpart, 32, 64);
    const float invl = 1.f / lpart;
    const size_t orow = (size_t)(b * S_ + qrow) * (NH_ * HD_) + (size_t)h * HD_;
#pragma unroll
    for (int dt = 0; dt < 8; ++dt) {
        bf16x4 ov = {(__bf16)(o[dt][0] * invl), (__bf16)(o[dt][1] * invl),
                     (__bf16)(o[dt][2] * invl), (__bf16)(o[dt][3] * invl)};
        *reinterpret_cast<bf16x4*>(&aout[orow + dt * 16 + quad * 4]) = ov;
    }
}

// ---------------------------------------------------------------------------
extern "C" void kernel_launch(void* const* d_in, const int* in_sizes, int n_in,
                              void* d_out, int out_size, void* d_ws,
                              size_t ws_size, hipStream_t stream) {
    const float* x     = (const float*)d_in[0];
    const float* w_in  = (const float*)d_in[1];
    const float* w_out = (const float*)d_in[2];
    const float* qw    = (const float*)d_in[3];
    const float* kw    = (const float*)d_in[4];
    float* out = (float*)d_out;

    const int M = B_ * S_;  // 4096
    // workspace (bytes), peak 96 MiB:
    //   [0,48M) qkv_bf16 | [48M,56M) w_out_bf16 | [56M,72M) x_bf16/attn_bf16
    //   [72M,96M) w_in_bf16
    char* ws = (char*)d_ws;
    __bf16* qkv_b   = (__bf16*)(ws);
    __bf16* w_out_b = (__bf16*)(ws + (size_t)50331648);
    __bf16* x_b     = (__bf16*)(ws + (size_t)58720256);
    __bf16* attn_b  = x_b;  // x_bf16 dead after GEMM1
    __bf16* w_in_b  = (__bf16*)(ws + (size_t)75497472);

    dim3 blk(256);

    // single fused cast launch: x, w_in, w_out
    {
        const int na4 = (M * HID_) / 4;          // 2,097,152
        const int nb4 = (QKV_ * HID_) / 4;       // 3,145,728
        const int nc4 = (HID_ * NH_ * HD_) / 4;  // 1,048,576
        const int tot = na4 + nb4 + nc4;
        cast3_f32_bf16<<<dim3((tot + 255) / 256), blk, 0, stream>>>(
            x, x_b, na4, w_in, w_in_b, nb4, w_out, w_out_b, nc4);
    }

    // qkv = x @ w_in^T   (4096 x 6144 x 2048): 768 blocks = 3 full CU-rounds
    gemm_bt_8ph<__bf16><<<dim3((M / 128) * (QKV_ / 256)), dim3(512), 0,
                          stream>>>(x_b, w_in_b, qkv_b, M, QKV_, HID_);
    // rmsnorm + rope on q and k, in place
    normrope_kernel<<<dim3(M, 2), blk, 0, stream>>>(qkv_b, qw, kw);
    // causal MFMA flash attention: 128-row Q-tiles, 8 waves, XCD-swizzled
    attn_mfma<<<dim3((S_ / 128) * B_ * NH_), dim3(512), 0, stream>>>(
        qkv_b, attn_b);
    // out = attn @ w_out^T  (4096 x 2048 x 2048): 256 blocks = 1 per CU
    gemm_bt_8ph<float><<<dim3((M / 128) * (HID_ / 256)), dim3(512), 0,
                         stream>>>(attn_b, w_out_b, out, M, HID_, NH_ * HD_);
}